// Round 9
// baseline (220.085 us; speedup 1.0000x reference)
//
#include <hip/hip_runtime.h>
#include <hip/hip_bf16.h>

// KANLayer: out = x @ Wb^T + silu(x) @ sum_g(Ws)^T
// R9: (a) prep_x FUSED into GEMM: stage A from fp32 x, silu+bf16 convert in
//         registers during staging (kills one dispatch + 67MB A' round-trip).
//     (b) LDS slot stride padded 2048B->2080B (520 words = 8 mod 32): bank math
//         now conflict-free for BOTH coalesced-pattern ds_writes and b128 frag
//         reads (R8's 8.4M conflicts came from ks-component = 0 mod 32).
//     Keeps: R8 register staging, dbuf + 1 barrier/iter, XCD swizzle, 128x128.

#define BATCH 8192
#define IN_F 1024
#define OUT_F 1024
#define KP 2048
#define SLOT 1040         // ushort elems per kslot (2080 B, padded)
#define BUF (4 * SLOT)    // 4160 elems per buffer per matrix

typedef unsigned short ushort_t;
typedef __attribute__((ext_vector_type(8))) short short8;
typedef __attribute__((ext_vector_type(4))) float f32x4;

__device__ __forceinline__ ushort_t f2bf(float f) {
  union { float f; unsigned int u; } v;
  v.f = f;
  unsigned int u = v.u;
  u += 0x7fffu + ((u >> 16) & 1u);  // RNE
  return (ushort_t)(u >> 16);
}

__device__ __forceinline__ ushort4 cvt4(float4 v, bool do_silu) {
  if (do_silu) {
    v.x = v.x / (1.0f + __expf(-v.x));
    v.y = v.y / (1.0f + __expf(-v.y));
    v.z = v.z / (1.0f + __expf(-v.z));
    v.w = v.w / (1.0f + __expf(-v.w));
  }
  ushort4 r;
  r.x = f2bf(v.x); r.y = f2bf(v.y); r.z = f2bf(v.z); r.w = f2bf(v.w);
  return r;
}

// ---------------- prep_w: W' = [Wb | sum_g Ws] bf16 [1024][2048] ----------
__global__ __launch_bounds__(256) void prep_w(
    const float* __restrict__ Wb, const float* __restrict__ Ws,
    ushort_t* __restrict__ Wpack) {
  const int blk = blockIdx.x;
  const int t = threadIdx.x;
  if (blk < 1024) {
    const int idx = blk * 256 + t;
    const int o = idx >> 8;
    const int i0 = (idx & 255) << 2;
    ushort_t vs[4];
#pragma unroll
    for (int j = 0; j < 4; ++j) {
      const float4* p = (const float4*)(Ws + ((((size_t)o << 10) + i0 + j) << 3));
      const float4 a = p[0];
      const float4 b = p[1];
      vs[j] = f2bf(((a.x + a.y) + (a.z + a.w)) + ((b.x + b.y) + (b.z + b.w)));
    }
    *(ushort4*)(Wpack + ((size_t)o << 11) + IN_F + i0) = *(ushort4*)vs;
  } else {
    const int idx = (blk - 1024) * 256 + t;
    const int o = idx >> 8;
    const int c = (idx & 255) << 2;
    const float4 w = *(const float4*)(Wb + ((size_t)o << 10) + c);
    ushort4 v;
    v.x = f2bf(w.x); v.y = f2bf(w.y); v.z = f2bf(w.z); v.w = f2bf(w.w);
    *(ushort4*)(Wpack + ((size_t)o << 11) + c) = v;
  }
}

// ---------------- fused GEMM ----------------
// C[M][N] = [bf16(x)|bf16(silu x)] @ W'^T. 128x128 tile, BK=32, 256 thr,
// 4 waves, wave tile 64x64 (4x4 16x16x32 frags). Grid (8,64)=512, 2/CU.
// LDS per matrix per buffer: [kslot 0..3 stride 1040][row 0..127][8 elems].
// A staged from fp32 x: thread t covers (row = t>>3 + j*32, q = t&7) j=0..3,
//   16B fp32 loads (coalesced), convert->ds_write_b64 at
//   elem = (q>>1)*SLOT + row*8 + (q&1)*4   (conflict-free, see bank math).
// B staged bf16: thread t covers (row = t>>2 [+64], ks = t&3), 16B loads,
//   ds_write_b128 at elem = ks*SLOT + row*8 (conflict-free).
__global__ __launch_bounds__(256) void gemm_fused(
    const float* __restrict__ x,     // [BATCH][IN_F] fp32
    const ushort_t* __restrict__ W,  // [OUT_F][KP] bf16
    float* __restrict__ C) {         // [BATCH][OUT_F] fp32
  __shared__ ushort_t As[2 * BUF];
  __shared__ ushort_t Bs[2 * BUF];

  const int t = threadIdx.x;
  const int flat = blockIdx.y * 8 + blockIdx.x;
  const int xcd = flat & 7;
  const int local = flat >> 3;           // 0..63
  const int nt = local >> 3;             // N-tile 0..7
  const int mt = xcd * 8 + (local & 7);  // M-tile 0..63 (XCD-local x slab)

  const int lane = t & 63;
  const int wave = t >> 6;
  const int wr = wave >> 1;
  const int wc = wave & 1;

  // --- A staging addressing (from x, fp32) ---
  const int ar0 = t >> 3;  // 0..31, rows ar0 + j*32
  const int aq = t & 7;    // 16B chunk within 128B row-window
  const float* a_gp = x + ((size_t)(mt * 128 + ar0)) * IN_F + aq * 4;
  const int a_elem0 = (aq >> 1) * SLOT + (ar0 << 3) + (aq & 1) * 4;  // + j*256

  // --- B staging addressing (from Wpack, bf16) ---
  const int br0 = t >> 2;  // 0..63, rows br0, br0+64
  const int bks = t & 3;
  const ushort_t* b_gp = W + ((size_t)(nt * 128 + br0)) * KP + bks * 8;
  const int b_elem0 = bks * SLOT + (br0 << 3);  // second row: +512

  f32x4 acc[4][4];
#pragma unroll
  for (int mi = 0; mi < 4; ++mi)
#pragma unroll
    for (int ni = 0; ni < 4; ++ni) acc[mi][ni] = (f32x4){0.f, 0.f, 0.f, 0.f};

  // fragment read addressing
  const int ks1040 = (lane >> 4) * SLOT;
  const int arow = wr * 64 + (lane & 15);
  const int brow = wc * 64 + (lane & 15);

  // ---- prologue: stage tile 0 into buffer 0 (k0=0 -> plain convert) ----
  {
    float4 fa[4];
    short8 fb0, fb1;
#pragma unroll
    for (int j = 0; j < 4; ++j) fa[j] = *(const float4*)(a_gp + j * 32 * IN_F);
    fb0 = *(const short8*)(b_gp);
    fb1 = *(const short8*)(b_gp + (size_t)64 * KP);
#pragma unroll
    for (int j = 0; j < 4; ++j)
      *(ushort4*)(As + a_elem0 + j * 256) = cvt4(fa[j], false);
    *(short8*)(Bs + b_elem0) = fb0;
    *(short8*)(Bs + b_elem0 + 512) = fb1;
  }
  __syncthreads();

  int poff = 0;
  for (int k0 = 0; k0 < KP; k0 += 32) {
    const bool more = (k0 + 32) < KP;
    const int kn = k0 + 32;
    const int kx = kn & 1023;          // x column base for next tile
    const bool silu_n = kn >= IN_F;    // next tile in silu half?

    // 1) prefetch next tile into registers (in flight during MFMA)
    float4 fa[4];
    short8 fb0, fb1;
    if (more) {
#pragma unroll
      for (int j = 0; j < 4; ++j) fa[j] = *(const float4*)(a_gp + kx + j * 32 * IN_F);
      fb0 = *(const short8*)(b_gp + kn);
      fb1 = *(const short8*)(b_gp + kn + (size_t)64 * KP);
    }

    // 2) fragment reads from current buffer
    const ushort_t* ab = As + poff + ks1040;
    const ushort_t* bb = Bs + poff + ks1040;
    short8 af[4], bfr[4];
#pragma unroll
    for (int mi = 0; mi < 4; ++mi)
      af[mi] = *(const short8*)(ab + ((arow + mi * 16) << 3));
#pragma unroll
    for (int ni = 0; ni < 4; ++ni)
      bfr[ni] = *(const short8*)(bb + ((brow + ni * 16) << 3));

    // 3) compute (covers prefetch flight)
#pragma unroll
    for (int mi = 0; mi < 4; ++mi)
#pragma unroll
      for (int ni = 0; ni < 4; ++ni)
        acc[mi][ni] = __builtin_amdgcn_mfma_f32_16x16x32_bf16(af[mi], bfr[ni], acc[mi][ni], 0, 0, 0);

    // 4) convert + stage into other buffer; single barrier
    if (more) {
      const int qoff = poff ^ BUF;
#pragma unroll
      for (int j = 0; j < 4; ++j)
        *(ushort4*)(As + qoff + a_elem0 + j * 256) = cvt4(fa[j], silu_n);
      *(short8*)(Bs + qoff + b_elem0) = fb0;
      *(short8*)(Bs + qoff + b_elem0 + 512) = fb1;
      __syncthreads();
    }
    poff ^= BUF;
  }

  // epilogue: C/D layout col=lane&15, row=(lane>>4)*4+reg
  const int col0 = nt * 128 + wc * 64 + (lane & 15);
  const int row0 = mt * 128 + wr * 64 + ((lane >> 4) << 2);
#pragma unroll
  for (int mi = 0; mi < 4; ++mi)
#pragma unroll
    for (int ni = 0; ni < 4; ++ni) {
      float* cp = C + (size_t)(row0 + mi * 16) * OUT_F + col0 + ni * 16;
#pragma unroll
      for (int rr = 0; rr < 4; ++rr) cp[(size_t)rr * OUT_F] = acc[mi][ni][rr];
    }
}

extern "C" void kernel_launch(void* const* d_in, const int* in_sizes, int n_in,
                              void* d_out, int out_size, void* d_ws, size_t ws_size,
                              hipStream_t stream) {
  const float* x = (const float*)d_in[0];
  const float* wb = (const float*)d_in[1];
  const float* ws = (const float*)d_in[2];
  float* out = (float*)d_out;

  ushort_t* Wpack = (ushort_t*)d_ws;  // 4 MB

  prep_w<<<2048, 256, 0, stream>>>(wb, ws, Wpack);
  gemm_fused<<<dim3(OUT_F / 128, BATCH / 128), 256, 0, stream>>>(x, Wpack, out);
}